// Round 3
// baseline (35.576 us; speedup 1.0000x reference)
//
#include <hip/hip_runtime.h>

// Problem constants (match reference setup_inputs)
#define PN 16
#define PC 8
#define PH 512
#define PW 1024
#define PJ 8

// ---------------------------------------------------------------------------
// Kernel 1: soft-argmax expected position, 8 consecutive rows per wave.
// Wave g owns rows g*8..g*8+7 — all in the same (n,c), so the 24-int param
// check is done once per wave (8x fewer checks than 1-row/wave) and the
// needed-rows test reduces to an 8-bit mask over h in [h0, h0+7].
// Grid: 2048 blocks x 256 threads = 8192 waves covering 65536 rows.
// Busy waves read up to 32KB contiguous. ~78% of rows skipped (unneeded).
// ---------------------------------------------------------------------------
__global__ __launch_bounds__(256) void pos_kernel(const float* __restrict__ logits,
                                                  const int* __restrict__ params,
                                                  float* __restrict__ pos) {
    const int gwave = (blockIdx.x * blockDim.x + threadIdx.x) >> 6;  // 0..8191
    const int lane = threadIdx.x & 63;

    const int n = gwave >> 9;            // 512 waves per sample
    const int c = (gwave >> 6) & (PC - 1);
    const int h0 = (gwave & 63) << 3;    // first of 8 h's

    // Build 8-bit mask of needed rows among h0..h0+7.
    // Row (n,c,h) needed iff some j: ch==c and start <= h <= end (inclusive
    // end, since diff[z] = pos[z] - pos[z+1] touches rows start..end).
    const int* pp = params + n * PJ * 3;
    unsigned mask = 0;
#pragma unroll
    for (int j = 0; j < PJ; ++j) {
        const int s = pp[j * 3 + 0];
        const int e = pp[j * 3 + 1];
        const int ch = pp[j * 3 + 2];
        if (ch == c) {
            const int lo = (s > h0) ? s : h0;
            const int hi = (e < h0 + 7) ? e : h0 + 7;
            if (lo <= hi) mask |= ((1u << (hi - lo + 1)) - 1u) << (lo - h0);
        }
    }
    if (!mask) return;  // wave-uniform exit

    const float* rowbase = logits + ((size_t)gwave << 3) * PW;

    for (int k = 0; k < 8; ++k) {
        if (!((mask >> k) & 1u)) continue;  // wave-uniform
        const float* row = rowbase + (size_t)k * PW;

        float v[16];
#pragma unroll
        for (int q = 0; q < 4; ++q) {
            float4 f = *reinterpret_cast<const float4*>(row + q * 256 + lane * 4);
            v[q * 4 + 0] = f.x;
            v[q * 4 + 1] = f.y;
            v[q * 4 + 2] = f.z;
            v[q * 4 + 3] = f.w;
        }

        float m = v[0];
#pragma unroll
        for (int i = 1; i < 16; ++i) m = fmaxf(m, v[i]);
#pragma unroll
        for (int off = 32; off > 0; off >>= 1) m = fmaxf(m, __shfl_xor(m, off));

        float s = 0.f, sw = 0.f;
#pragma unroll
        for (int q = 0; q < 4; ++q) {
#pragma unroll
            for (int j = 0; j < 4; ++j) {
                float e = __expf(v[q * 4 + j] - m);
                s += e;
                sw += e * (float)(q * 256 + lane * 4 + j);
            }
        }
#pragma unroll
        for (int off = 32; off > 0; off >>= 1) {
            s += __shfl_xor(s, off);
            sw += __shfl_xor(sw, off);
        }

        if (lane == 0) pos[(gwave << 3) + k] = sw / s;
    }
}

// ---------------------------------------------------------------------------
// Kernel 2 (fused loss + finalize): single block, 16 waves.
// Each wave handles 8 (n,j) pairs (p = wave, wave+16, ...); per pair the 64
// lanes stride the z range. Wave partials -> LDS -> serial reduce by thread 0.
// Fixed summation order => deterministic across replays.
// ---------------------------------------------------------------------------
__global__ __launch_bounds__(1024) void loss_kernel(const float* __restrict__ pos,
                                                    const int* __restrict__ params,
                                                    float* __restrict__ out) {
    __shared__ float ssum[16], scnt[16];
    const int wave = threadIdx.x >> 6;
    const int lane = threadIdx.x & 63;

    float sum = 0.f, cnt = 0.f;
    for (int p = wave; p < PN * PJ; p += 16) {
        const int* pp = params + p * 3;
        const int start = pp[0];
        const int end = pp[1];
        const int ch = pp[2];
        const float* q = pos + ((size_t)(p >> 3) * PC + ch) * PH;
        for (int z = start + lane; z < end; z += 64) {
            float d = q[z] - q[z + 1];
            float x = fabsf(d);
            sum += (x < 1.f) ? 0.5f * d * d : (x - 0.5f);
            cnt += 1.f;
        }
    }
#pragma unroll
    for (int off = 32; off > 0; off >>= 1) {
        sum += __shfl_xor(sum, off);
        cnt += __shfl_xor(cnt, off);
    }
    if (lane == 0) { ssum[wave] = sum; scnt[wave] = cnt; }
    __syncthreads();
    if (threadIdx.x == 0) {
        float S = 0.f, Cc = 0.f;
#pragma unroll
        for (int i = 0; i < 16; ++i) { S += ssum[i]; Cc += scnt[i]; }
        out[0] = S / Cc;
    }
}

extern "C" void kernel_launch(void* const* d_in, const int* in_sizes, int n_in,
                              void* d_out, int out_size, void* d_ws, size_t ws_size,
                              hipStream_t stream) {
    const float* logits = (const float*)d_in[0];
    const int* params = (const int*)d_in[1];
    float* out = (float*)d_out;

    // Workspace: [0 .. N*C*H) floats = pos array (only needed rows written;
    // unneeded entries are never read by loss_kernel, poison is harmless).
    float* pos = (float*)d_ws;

    pos_kernel<<<2048, 256, 0, stream>>>(logits, params, pos);
    loss_kernel<<<1, 1024, 0, stream>>>(pos, params, out);
}